// Round 6
// baseline (536.544 us; speedup 1.0000x reference)
//
#include <hip/hip_runtime.h>
#include <hip/hip_bf16.h>

typedef __hip_bfloat16 bf16;

#define NGRAPH 128

// ---------------- degree histogram ----------------
__global__ __launch_bounds__(256) void deg_kernel(const int* __restrict__ ei,
                                                  int* __restrict__ deg, int E, int N) {
    int e = blockIdx.x * 256 + threadIdx.x;
    if (e < E) {
        int d = ei[E + e];                 // dst = ei[1][e]
        d = max(0, min(d, N - 1));
        atomicAdd(&deg[d], 1);
    }
}

// ---------------- scan: per-block sums ----------------
__global__ __launch_bounds__(256) void scan1_kernel(const int* __restrict__ deg,
                                                    int* __restrict__ bsum, int N) {
    __shared__ int tmp[256];
    int i = blockIdx.x * 256 + threadIdx.x;
    tmp[threadIdx.x] = (i < N) ? deg[i] : 0;
    __syncthreads();
    for (int off = 128; off > 0; off >>= 1) {
        if (threadIdx.x < off) tmp[threadIdx.x] += tmp[threadIdx.x + off];
        __syncthreads();
    }
    if (threadIdx.x == 0) bsum[blockIdx.x] = tmp[0];
}

// ---------------- scan: exclusive scan of block sums ----------------
__global__ __launch_bounds__(256) void scan2_kernel(const int* __restrict__ bsum,
                                                    int* __restrict__ boff, int nb) {
    __shared__ int tmp[256];
    __shared__ int carry;
    int tid = threadIdx.x;
    if (tid == 0) carry = 0;
    __syncthreads();
    for (int base = 0; base < nb; base += 256) {
        int i = base + tid;
        int v = (i < nb) ? bsum[i] : 0;
        tmp[tid] = v;
        __syncthreads();
        for (int off = 1; off < 256; off <<= 1) {
            int t = (tid >= off) ? tmp[tid - off] : 0;
            __syncthreads();
            tmp[tid] += t;
            __syncthreads();
        }
        if (i < nb) boff[i] = carry + tmp[tid] - v;
        __syncthreads();
        if (tid == 0) carry += tmp[255];
        __syncthreads();
    }
}

// ---------------- scan: per-element row_start + dinv ----------------
__global__ __launch_bounds__(256) void scan3_kernel(const int* __restrict__ deg,
                                                    const int* __restrict__ boff,
                                                    int* __restrict__ row_start,
                                                    float* __restrict__ dinv, int N) {
    __shared__ int tmp[256];
    int i = blockIdx.x * 256 + threadIdx.x;
    int v = (i < N) ? deg[i] : 0;
    tmp[threadIdx.x] = v;
    __syncthreads();
    for (int off = 1; off < 256; off <<= 1) {
        int t = (threadIdx.x >= off) ? tmp[threadIdx.x - off] : 0;
        __syncthreads();
        tmp[threadIdx.x] += t;
        __syncthreads();
    }
    if (i < N) {
        int excl = tmp[threadIdx.x] - v;
        int rs = boff[blockIdx.x] + excl;
        row_start[i] = rs;
        if (i == N - 1) row_start[N] = rs + v;
        dinv[i] = rsqrtf((float)(v + 1));   // +1 self loop
    }
}

// ---------------- CSR fill (dst-sorted src list) ----------------
__global__ __launch_bounds__(256) void fill_kernel(const int* __restrict__ ei,
                                                   const int* __restrict__ row_start,
                                                   int* __restrict__ cursor,
                                                   int* __restrict__ csr_src, int E, int N) {
    int e = blockIdx.x * 256 + threadIdx.x;
    if (e < E) {
        int s = ei[e];     s = max(0, min(s, N - 1));
        int d = ei[E + e]; d = max(0, min(d, N - 1));
        int pos = row_start[d] + atomicAdd(&cursor[d], 1);
        if (pos >= 0 && pos < E) csr_src[pos] = s;
    }
}

// ---------------- P1 = (x @ W1) * dinv  (wave-per-node, grid-stride) ----------------
__global__ __launch_bounds__(256) void proj_kernel(const float* __restrict__ A,
                                                   const float* __restrict__ W,
                                                   const float* __restrict__ dinv,
                                                   bf16* __restrict__ P, int N) {
    __shared__ float Wl[4096];
    for (int i = threadIdx.x; i < 4096; i += 256) Wl[i] = W[i];
    __syncthreads();
    int lane = threadIdx.x & 63;
    int wid = (blockIdx.x * 256 + threadIdx.x) >> 6;
    int nwaves = (gridDim.x * 256) >> 6;
    for (int node = wid; node < N; node += nwaves) {
        float a = A[(size_t)node * 64 + lane];
        float acc = 0.f;
#pragma unroll
        for (int k = 0; k < 64; ++k) acc += __shfl(a, k) * Wl[k * 64 + lane];
        P[(size_t)node * 64 + lane] = __float2bfloat16(acc * dinv[node]);
    }
}

// ---- unpack uint4 (8 bf16) and accumulate with weight w ----
__device__ __forceinline__ void acc_bf8(float* acc, uint4 v, float w) {
    unsigned int u[4] = {v.x, v.y, v.z, v.w};
#pragma unroll
    for (int m = 0; m < 4; ++m) {
        float lo = __uint_as_float(u[m] << 16);
        float hi = __uint_as_float(u[m] & 0xffff0000u);
        acc[2 * m]     += w * lo;
        acc[2 * m + 1] += w * hi;
    }
}

// ---- wide gather: 8 rows per load instruction, unroll x2 (16 rows in flight).
//      On return, EVERY lane holds in acc[0..7] the neighbor-sum for features
//      c*8 .. c*8+7 (c = lane&7), identical across the 8 r-groups. ----
__device__ __forceinline__ void gather_sum8(float* acc,
                                            const bf16* __restrict__ P,
                                            const int* __restrict__ csr_src,
                                            int beg, int end, int r, int c) {
#pragma unroll
    for (int k = 0; k < 8; ++k) acc[k] = 0.f;
    for (int i = beg; i < end; i += 16) {
        int r0 = i + r, r1 = i + 8 + r;
        int ok0 = (r0 < end), ok1 = (r1 < end);
        int s0 = ok0 ? csr_src[r0] : 0;
        int s1 = ok1 ? csr_src[r1] : 0;
        float w0 = ok0 ? 1.f : 0.f;
        float w1 = ok1 ? 1.f : 0.f;
        uint4 v0 = *(const uint4*)(P + (size_t)s0 * 64 + c * 8);
        uint4 v1 = *(const uint4*)(P + (size_t)s1 * 64 + c * 8);
        acc_bf8(acc, v0, w0);
        acc_bf8(acc, v1, w1);
    }
    // butterfly-reduce across the 8 r-groups (lane bits 3..5)
#pragma unroll
    for (int mask = 8; mask <= 32; mask <<= 1) {
#pragma unroll
        for (int k = 0; k < 8; ++k) acc[k] += __shfl_xor(acc[k], mask);
    }
}

// ---- layer1 aggregate + fused layer2 projection ----
__global__ __launch_bounds__(256) void agg_proj_kernel(const bf16* __restrict__ P1,
                                                       const int* __restrict__ row_start,
                                                       const int* __restrict__ csr_src,
                                                       const float* __restrict__ dinv,
                                                       const float* __restrict__ b1,
                                                       const float* __restrict__ W2,
                                                       bf16* __restrict__ P2, int N) {
    __shared__ float Wl[4096];
    for (int i = threadIdx.x; i < 4096; i += 256) Wl[i] = W2[i];
    __syncthreads();
    int lane = threadIdx.x & 63;
    int r = lane >> 3, c = lane & 7;
    float bb[8];
#pragma unroll
    for (int k = 0; k < 8; ++k) bb[k] = b1[c * 8 + k];
    int wid = (blockIdx.x * 256 + threadIdx.x) >> 6;
    int nwaves = (gridDim.x * 256) >> 6;
    for (int node = wid; node < N; node += nwaves) {
        float acc[8];
        gather_sum8(acc, P1, csr_src, row_start[node], row_start[node + 1], r, c);
        // self-loop chunk (added once per lane, after reduction)
        uint4 vs = *(const uint4*)(P1 + (size_t)node * 64 + c * 8);
        acc_bf8(acc, vs, 1.f);
        float dv = dinv[node];
        float h[8];
#pragma unroll
        for (int k = 0; k < 8; ++k) h[k] = fmaxf(acc[k] * dv + bb[k], 0.f);
        // fused projection: P2[node][lane] = (h1 @ W2)[lane] * dinv
        float acc2 = 0.f;
#pragma unroll
        for (int c2 = 0; c2 < 8; ++c2) {
#pragma unroll
            for (int j = 0; j < 8; ++j) {
                acc2 += __shfl(h[j], c2) * Wl[(c2 * 8 + j) * 64 + lane];
            }
        }
        P2[(size_t)node * 64 + lane] = __float2bfloat16(acc2 * dv);
    }
}

// ---- layer2 aggregate + fused mean-pool accumulation ----
__global__ __launch_bounds__(256) void agg_pool_kernel(const bf16* __restrict__ P2,
                                                       const int* __restrict__ row_start,
                                                       const int* __restrict__ csr_src,
                                                       const float* __restrict__ dinv,
                                                       const float* __restrict__ b2,
                                                       const int* __restrict__ batch,
                                                       float* __restrict__ out_h,
                                                       float* __restrict__ accum, int N) {
    int lane = threadIdx.x & 63;
    int r = lane >> 3, c = lane & 7;
    float bb[8];
#pragma unroll
    for (int k = 0; k < 8; ++k) bb[k] = b2[c * 8 + k];
    int wid = (blockIdx.x * 256 + threadIdx.x) >> 6;
    int nwaves = (gridDim.x * 256) >> 6;
    for (int node = wid; node < N; node += nwaves) {
        float acc[8];
        gather_sum8(acc, P2, csr_src, row_start[node], row_start[node + 1], r, c);
        uint4 vs = *(const uint4*)(P2 + (size_t)node * 64 + c * 8);
        acc_bf8(acc, vs, 1.f);
        float dv = dinv[node];
        float h[8];
#pragma unroll
        for (int k = 0; k < 8; ++k) h[k] = acc[k] * dv + bb[k];
        if (r == 0) {
            float4 w0 = make_float4(h[0], h[1], h[2], h[3]);
            float4 w1 = make_float4(h[4], h[5], h[6], h[7]);
            *(float4*)(out_h + (size_t)node * 64 + c * 8)     = w0;
            *(float4*)(out_h + (size_t)node * 64 + c * 8 + 4) = w1;
            int g = batch[node];
            g = max(0, min(g, NGRAPH - 1));
#pragma unroll
            for (int k = 0; k < 8; ++k) atomicAdd(&accum[g * 64 + c * 8 + k], h[k]);
        }
    }
}

// ---------------- finalize pool (divide by count) + classifier head ----------------
__device__ __forceinline__ int lower_bound_dev(const int* a, int n, int key) {
    int lo = 0, hi = n;
    while (lo < hi) {
        int mid = (lo + hi) >> 1;
        if (a[mid] < key) lo = mid + 1; else hi = mid;
    }
    return lo;
}

__global__ __launch_bounds__(64) void final_kernel(const float* __restrict__ accum,
                                                   const int* __restrict__ batch,
                                                   const float* __restrict__ Wc1,
                                                   const float* __restrict__ bc1,
                                                   const float* __restrict__ Wc2,
                                                   const float* __restrict__ bc2,
                                                   float* __restrict__ out_reps,
                                                   float* __restrict__ out_logits, int N) {
    __shared__ float rep[64];
    __shared__ float t[64];
    int g = blockIdx.x;
    int f = threadIdx.x;
    int lo = lower_bound_dev(batch, N, g);
    int hi = lower_bound_dev(batch, N, g + 1);
    float cnt = (float)(hi - lo);
    float r = accum[g * 64 + f] / fmaxf(cnt, 1.f);
    out_reps[g * 64 + f] = r;
    rep[f] = r;
    __syncthreads();
    float acc = bc1[f];
#pragma unroll
    for (int k = 0; k < 64; ++k) acc += rep[k] * Wc1[k * 64 + f];
    t[f] = fmaxf(acc, 0.f);
    __syncthreads();
    if (f < 16) {
        float a2 = bc2[f];
#pragma unroll
        for (int k = 0; k < 64; ++k) a2 += t[k] * Wc2[k * 16 + f];
        out_logits[g * 16 + f] = a2;
    }
}

extern "C" void kernel_launch(void* const* d_in, const int* in_sizes, int n_in,
                              void* d_out, int out_size, void* d_ws, size_t ws_size,
                              hipStream_t stream) {
    const float* x    = (const float*)d_in[0];
    const int*   ei   = (const int*)d_in[1];
    const int*   batch= (const int*)d_in[2];
    const float* W1   = (const float*)d_in[3];
    const float* b1   = (const float*)d_in[4];
    const float* W2   = (const float*)d_in[5];
    const float* b2   = (const float*)d_in[6];
    const float* Wc1  = (const float*)d_in[7];
    const float* bc1  = (const float*)d_in[8];
    const float* Wc2  = (const float*)d_in[9];
    const float* bc2  = (const float*)d_in[10];

    const int N = in_sizes[2];          // 50000
    const int E = in_sizes[1] / 2;      // 800000

    // ---- workspace layout (~7.3 MB) ----
    char* ws = (char*)d_ws;
    size_t off = 0;
    auto alloc = [&](size_t bytes) { void* p = ws + off; off += (bytes + 255) & ~(size_t)255; return p; };
    int*   deg       = (int*)  alloc((size_t)N * 4);
    int*   cursor    = (int*)  alloc((size_t)N * 4);
    float* accum     = (float*)alloc((size_t)NGRAPH * 64 * 4);
    size_t zero_bytes = off;                       // deg + cursor + accum start at 0
    float* dinv      = (float*)alloc((size_t)N * 4);
    int*   row_start = (int*)  alloc((size_t)(N + 1) * 4);
    int*   bsum      = (int*)  alloc(1024);
    int*   boff      = (int*)  alloc(1024);
    int*   csr_src   = (int*)  alloc((size_t)E * 4);
    bf16*  P1        = (bf16*) alloc((size_t)N * 64 * 2);
    bf16*  P2        = (bf16*) alloc((size_t)N * 64 * 2);
    (void)ws_size; (void)n_in; (void)out_size;

    float* out_h      = (float*)d_out;                      // [N,64]
    float* out_reps   = out_h + (size_t)N * 64;             // [128,64]
    float* out_logits = out_reps + (size_t)NGRAPH * 64;     // [128,16]

    int nbE = (E + 255) / 256;
    int nbN = (N + 255) / 256;
    const int GS = 2048;                 // grid-stride blocks (8192 waves)

    hipMemsetAsync(d_ws, 0, zero_bytes, stream);
    deg_kernel<<<nbE, 256, 0, stream>>>(ei, deg, E, N);
    scan1_kernel<<<nbN, 256, 0, stream>>>(deg, bsum, N);
    scan2_kernel<<<1, 256, 0, stream>>>(bsum, boff, nbN);
    scan3_kernel<<<nbN, 256, 0, stream>>>(deg, boff, row_start, dinv, N);
    fill_kernel<<<nbE, 256, 0, stream>>>(ei, row_start, cursor, csr_src, E, N);

    proj_kernel<<<GS, 256, 0, stream>>>(x, W1, dinv, P1, N);
    agg_proj_kernel<<<GS, 256, 0, stream>>>(P1, row_start, csr_src, dinv, b1, W2, P2, N);
    agg_pool_kernel<<<GS, 256, 0, stream>>>(P2, row_start, csr_src, dinv, b2, batch,
                                            out_h, accum, N);
    final_kernel<<<NGRAPH, 64, 0, stream>>>(accum, batch, Wc1, bc1, Wc2, bc2,
                                            out_reps, out_logits, N);
}

// Round 7
// 324.664 us; speedup vs baseline: 1.6526x; 1.6526x over previous
//
#include <hip/hip_runtime.h>
#include <hip/hip_bf16.h>

typedef __hip_bfloat16 bf16;

#define NGRAPH 128

// ---------------- degree histogram ----------------
__global__ __launch_bounds__(256) void deg_kernel(const int* __restrict__ ei,
                                                  int* __restrict__ deg, int E, int N) {
    int e = blockIdx.x * 256 + threadIdx.x;
    if (e < E) {
        int d = ei[E + e];                 // dst = ei[1][e]
        d = max(0, min(d, N - 1));
        atomicAdd(&deg[d], 1);
    }
}

// ---------------- scan: per-block sums ----------------
__global__ __launch_bounds__(256) void scan1_kernel(const int* __restrict__ deg,
                                                    int* __restrict__ bsum, int N) {
    __shared__ int tmp[256];
    int i = blockIdx.x * 256 + threadIdx.x;
    tmp[threadIdx.x] = (i < N) ? deg[i] : 0;
    __syncthreads();
    for (int off = 128; off > 0; off >>= 1) {
        if (threadIdx.x < off) tmp[threadIdx.x] += tmp[threadIdx.x + off];
        __syncthreads();
    }
    if (threadIdx.x == 0) bsum[blockIdx.x] = tmp[0];
}

// ---------------- scan: exclusive scan of block sums ----------------
__global__ __launch_bounds__(256) void scan2_kernel(const int* __restrict__ bsum,
                                                    int* __restrict__ boff, int nb) {
    __shared__ int tmp[256];
    __shared__ int carry;
    int tid = threadIdx.x;
    if (tid == 0) carry = 0;
    __syncthreads();
    for (int base = 0; base < nb; base += 256) {
        int i = base + tid;
        int v = (i < nb) ? bsum[i] : 0;
        tmp[tid] = v;
        __syncthreads();
        for (int off = 1; off < 256; off <<= 1) {
            int t = (tid >= off) ? tmp[tid - off] : 0;
            __syncthreads();
            tmp[tid] += t;
            __syncthreads();
        }
        if (i < nb) boff[i] = carry + tmp[tid] - v;
        __syncthreads();
        if (tid == 0) carry += tmp[255];
        __syncthreads();
    }
}

// ---------------- scan: per-element row_start + dinv ----------------
__global__ __launch_bounds__(256) void scan3_kernel(const int* __restrict__ deg,
                                                    const int* __restrict__ boff,
                                                    int* __restrict__ row_start,
                                                    float* __restrict__ dinv, int N) {
    __shared__ int tmp[256];
    int i = blockIdx.x * 256 + threadIdx.x;
    int v = (i < N) ? deg[i] : 0;
    tmp[threadIdx.x] = v;
    __syncthreads();
    for (int off = 1; off < 256; off <<= 1) {
        int t = (threadIdx.x >= off) ? tmp[threadIdx.x - off] : 0;
        __syncthreads();
        tmp[threadIdx.x] += t;
        __syncthreads();
    }
    if (i < N) {
        int excl = tmp[threadIdx.x] - v;
        int rs = boff[blockIdx.x] + excl;
        row_start[i] = rs;
        if (i == N - 1) row_start[N] = rs + v;
        dinv[i] = rsqrtf((float)(v + 1));   // +1 self loop
    }
}

// ---------------- CSR fill (dst-sorted src list) ----------------
__global__ __launch_bounds__(256) void fill_kernel(const int* __restrict__ ei,
                                                   const int* __restrict__ row_start,
                                                   int* __restrict__ cursor,
                                                   int* __restrict__ csr_src, int E, int N) {
    int e = blockIdx.x * 256 + threadIdx.x;
    if (e < E) {
        int s = ei[e];     s = max(0, min(s, N - 1));
        int d = ei[E + e]; d = max(0, min(d, N - 1));
        int pos = row_start[d] + atomicAdd(&cursor[d], 1);
        if (pos >= 0 && pos < E) csr_src[pos] = s;
    }
}

// ---------------- P1 = (x @ W1) * dinv  (wave-per-node, grid-stride) ----------------
__global__ __launch_bounds__(256) void proj_kernel(const float* __restrict__ A,
                                                   const float* __restrict__ W,
                                                   const float* __restrict__ dinv,
                                                   bf16* __restrict__ P, int N) {
    __shared__ float Wl[4096];
    for (int i = threadIdx.x; i < 4096; i += 256) Wl[i] = W[i];
    __syncthreads();
    int lane = threadIdx.x & 63;
    int wid = (blockIdx.x * 256 + threadIdx.x) >> 6;
    int nwaves = (gridDim.x * 256) >> 6;
    for (int node = wid; node < N; node += nwaves) {
        float a = A[(size_t)node * 64 + lane];
        float acc = 0.f;
#pragma unroll
        for (int k = 0; k < 64; ++k) acc += __shfl(a, k) * Wl[k * 64 + lane];
        P[(size_t)node * 64 + lane] = __float2bfloat16(acc * dinv[node]);
    }
}

// ---- unpack uint4 (8 bf16) and accumulate with weight w ----
__device__ __forceinline__ void acc_bf8(float* acc, uint4 v, float w) {
    unsigned int u[4] = {v.x, v.y, v.z, v.w};
#pragma unroll
    for (int m = 0; m < 4; ++m) {
        float lo = __uint_as_float(u[m] << 16);
        float hi = __uint_as_float(u[m] & 0xffff0000u);
        acc[2 * m]     += w * lo;
        acc[2 * m + 1] += w * hi;
    }
}

// ---- wide gather: 8 rows per load instruction, unroll x2 (16 rows in flight).
//      On return, EVERY lane holds in acc[0..7] the neighbor-sum for features
//      c*8 .. c*8+7 (c = lane&7), identical across the 8 r-groups. ----
__device__ __forceinline__ void gather_sum8(float* acc,
                                            const bf16* __restrict__ P,
                                            const int* __restrict__ csr_src,
                                            int beg, int end, int r, int c) {
#pragma unroll
    for (int k = 0; k < 8; ++k) acc[k] = 0.f;
    for (int i = beg; i < end; i += 16) {
        int r0 = i + r, r1 = i + 8 + r;
        int ok0 = (r0 < end), ok1 = (r1 < end);
        int s0 = ok0 ? csr_src[r0] : 0;
        int s1 = ok1 ? csr_src[r1] : 0;
        float w0 = ok0 ? 1.f : 0.f;
        float w1 = ok1 ? 1.f : 0.f;
        uint4 v0 = *(const uint4*)(P + (size_t)s0 * 64 + c * 8);
        uint4 v1 = *(const uint4*)(P + (size_t)s1 * 64 + c * 8);
        acc_bf8(acc, v0, w0);
        acc_bf8(acc, v1, w1);
    }
    // butterfly-reduce across the 8 r-groups (lane bits 3..5)
#pragma unroll
    for (int mask = 8; mask <= 32; mask <<= 1) {
#pragma unroll
        for (int k = 0; k < 8; ++k) acc[k] += __shfl_xor(acc[k], mask);
    }
}

// ---- layer1 aggregate + fused layer2 projection ----
__global__ __launch_bounds__(256) void agg_proj_kernel(const bf16* __restrict__ P1,
                                                       const int* __restrict__ row_start,
                                                       const int* __restrict__ csr_src,
                                                       const float* __restrict__ dinv,
                                                       const float* __restrict__ b1,
                                                       const float* __restrict__ W2,
                                                       bf16* __restrict__ P2, int N) {
    __shared__ float Wl[4096];
    for (int i = threadIdx.x; i < 4096; i += 256) Wl[i] = W2[i];
    __syncthreads();
    int lane = threadIdx.x & 63;
    int r = lane >> 3, c = lane & 7;
    float bb[8];
#pragma unroll
    for (int k = 0; k < 8; ++k) bb[k] = b1[c * 8 + k];
    int wid = (blockIdx.x * 256 + threadIdx.x) >> 6;
    int nwaves = (gridDim.x * 256) >> 6;
    for (int node = wid; node < N; node += nwaves) {
        float acc[8];
        gather_sum8(acc, P1, csr_src, row_start[node], row_start[node + 1], r, c);
        // self-loop chunk (added once per lane, after reduction)
        uint4 vs = *(const uint4*)(P1 + (size_t)node * 64 + c * 8);
        acc_bf8(acc, vs, 1.f);
        float dv = dinv[node];
        float h[8];
#pragma unroll
        for (int k = 0; k < 8; ++k) h[k] = fmaxf(acc[k] * dv + bb[k], 0.f);
        // fused projection: P2[node][lane] = (h1 @ W2)[lane] * dinv
        float acc2 = 0.f;
#pragma unroll
        for (int c2 = 0; c2 < 8; ++c2) {
#pragma unroll
            for (int j = 0; j < 8; ++j) {
                acc2 += __shfl(h[j], c2) * Wl[(c2 * 8 + j) * 64 + lane];
            }
        }
        P2[(size_t)node * 64 + lane] = __float2bfloat16(acc2 * dv);
    }
}

// ---- layer2 aggregate + fused mean-pool accumulation ----
__global__ __launch_bounds__(256) void agg_pool_kernel(const bf16* __restrict__ P2,
                                                       const int* __restrict__ row_start,
                                                       const int* __restrict__ csr_src,
                                                       const float* __restrict__ dinv,
                                                       const float* __restrict__ b2,
                                                       const int* __restrict__ batch,
                                                       float* __restrict__ out_h,
                                                       float* __restrict__ accum, int N) {
    int lane = threadIdx.x & 63;
    int r = lane >> 3, c = lane & 7;
    float bb[8];
#pragma unroll
    for (int k = 0; k < 8; ++k) bb[k] = b2[c * 8 + k];
    // transpose source lane: holds c' = lane>>3, i.e. features (lane>>3)*8+k
    int src = ((lane & 7) << 3) | (lane >> 3);
    int wid = (blockIdx.x * 256 + threadIdx.x) >> 6;
    int nwaves = (gridDim.x * 256) >> 6;
    for (int node = wid; node < N; node += nwaves) {
        float acc[8];
        gather_sum8(acc, P2, csr_src, row_start[node], row_start[node + 1], r, c);
        uint4 vs = *(const uint4*)(P2 + (size_t)node * 64 + c * 8);
        acc_bf8(acc, vs, 1.f);
        float dv = dinv[node];
        float h[8];
#pragma unroll
        for (int k = 0; k < 8; ++k) h[k] = acc[k] * dv + bb[k];
        // in-register transpose: lane l ends up holding feature l
        //   feature l is h[l&7] on any lane with c == l>>3; use lane src.
        float val = 0.f;
#pragma unroll
        for (int k = 0; k < 8; ++k) {
            float t = __shfl(h[k], src);
            val = ((lane & 7) == k) ? t : val;
        }
        // coalesced wave-wide store (256 B contiguous) + ONE wave-wide atomic
        out_h[(size_t)node * 64 + lane] = val;
        int g = batch[node];
        g = max(0, min(g, NGRAPH - 1));
        atomicAdd(&accum[g * 64 + lane], val);
    }
}

// ---------------- finalize pool (divide by count) + classifier head ----------------
__device__ __forceinline__ int lower_bound_dev(const int* a, int n, int key) {
    int lo = 0, hi = n;
    while (lo < hi) {
        int mid = (lo + hi) >> 1;
        if (a[mid] < key) lo = mid + 1; else hi = mid;
    }
    return lo;
}

__global__ __launch_bounds__(64) void final_kernel(const float* __restrict__ accum,
                                                   const int* __restrict__ batch,
                                                   const float* __restrict__ Wc1,
                                                   const float* __restrict__ bc1,
                                                   const float* __restrict__ Wc2,
                                                   const float* __restrict__ bc2,
                                                   float* __restrict__ out_reps,
                                                   float* __restrict__ out_logits, int N) {
    __shared__ float rep[64];
    __shared__ float t[64];
    int g = blockIdx.x;
    int f = threadIdx.x;
    int lo = lower_bound_dev(batch, N, g);
    int hi = lower_bound_dev(batch, N, g + 1);
    float cnt = (float)(hi - lo);
    float r = accum[g * 64 + f] / fmaxf(cnt, 1.f);
    out_reps[g * 64 + f] = r;
    rep[f] = r;
    __syncthreads();
    float acc = bc1[f];
#pragma unroll
    for (int k = 0; k < 64; ++k) acc += rep[k] * Wc1[k * 64 + f];
    t[f] = fmaxf(acc, 0.f);
    __syncthreads();
    if (f < 16) {
        float a2 = bc2[f];
#pragma unroll
        for (int k = 0; k < 64; ++k) a2 += t[k] * Wc2[k * 16 + f];
        out_logits[g * 16 + f] = a2;
    }
}

extern "C" void kernel_launch(void* const* d_in, const int* in_sizes, int n_in,
                              void* d_out, int out_size, void* d_ws, size_t ws_size,
                              hipStream_t stream) {
    const float* x    = (const float*)d_in[0];
    const int*   ei   = (const int*)d_in[1];
    const int*   batch= (const int*)d_in[2];
    const float* W1   = (const float*)d_in[3];
    const float* b1   = (const float*)d_in[4];
    const float* W2   = (const float*)d_in[5];
    const float* b2   = (const float*)d_in[6];
    const float* Wc1  = (const float*)d_in[7];
    const float* bc1  = (const float*)d_in[8];
    const float* Wc2  = (const float*)d_in[9];
    const float* bc2  = (const float*)d_in[10];

    const int N = in_sizes[2];          // 50000
    const int E = in_sizes[1] / 2;      // 800000

    // ---- workspace layout (~7.3 MB) ----
    char* ws = (char*)d_ws;
    size_t off = 0;
    auto alloc = [&](size_t bytes) { void* p = ws + off; off += (bytes + 255) & ~(size_t)255; return p; };
    int*   deg       = (int*)  alloc((size_t)N * 4);
    int*   cursor    = (int*)  alloc((size_t)N * 4);
    float* accum     = (float*)alloc((size_t)NGRAPH * 64 * 4);
    size_t zero_bytes = off;                       // deg + cursor + accum start at 0
    float* dinv      = (float*)alloc((size_t)N * 4);
    int*   row_start = (int*)  alloc((size_t)(N + 1) * 4);
    int*   bsum      = (int*)  alloc(1024);
    int*   boff      = (int*)  alloc(1024);
    int*   csr_src   = (int*)  alloc((size_t)E * 4);
    bf16*  P1        = (bf16*) alloc((size_t)N * 64 * 2);
    bf16*  P2        = (bf16*) alloc((size_t)N * 64 * 2);
    (void)ws_size; (void)n_in; (void)out_size;

    float* out_h      = (float*)d_out;                      // [N,64]
    float* out_reps   = out_h + (size_t)N * 64;             // [128,64]
    float* out_logits = out_reps + (size_t)NGRAPH * 64;     // [128,16]

    int nbE = (E + 255) / 256;
    int nbN = (N + 255) / 256;
    const int GS = 2048;                 // grid-stride blocks (8192 waves)

    hipMemsetAsync(d_ws, 0, zero_bytes, stream);
    deg_kernel<<<nbE, 256, 0, stream>>>(ei, deg, E, N);
    scan1_kernel<<<nbN, 256, 0, stream>>>(deg, bsum, N);
    scan2_kernel<<<1, 256, 0, stream>>>(bsum, boff, nbN);
    scan3_kernel<<<nbN, 256, 0, stream>>>(deg, boff, row_start, dinv, N);
    fill_kernel<<<nbE, 256, 0, stream>>>(ei, row_start, cursor, csr_src, E, N);

    proj_kernel<<<GS, 256, 0, stream>>>(x, W1, dinv, P1, N);
    agg_proj_kernel<<<GS, 256, 0, stream>>>(P1, row_start, csr_src, dinv, b1, W2, P2, N);
    agg_pool_kernel<<<GS, 256, 0, stream>>>(P2, row_start, csr_src, dinv, b2, batch,
                                            out_h, accum, N);
    final_kernel<<<NGRAPH, 64, 0, stream>>>(accum, batch, Wc1, bc1, Wc2, bc2,
                                            out_reps, out_logits, N);
}